// Round 2
// baseline (942.346 us; speedup 1.0000x reference)
//
#include <hip/hip_runtime.h>
#include <hip/hip_bf16.h>
#include <hip/hip_fp16.h>

#define DEVINL __device__ __forceinline__

typedef __bf16 bf16x8 __attribute__((ext_vector_type(8)));
typedef float f32x4 __attribute__((ext_vector_type(4)));
typedef unsigned int u32x4 __attribute__((ext_vector_type(4)));

typedef __attribute__((address_space(1))) void void_g;
typedef __attribute__((address_space(3))) void void_l;

DEVINL float bf2f(unsigned short b) { return __uint_as_float(((unsigned int)b) << 16); }
DEVINL unsigned short f2bf(float f) {
  unsigned int u = __float_as_uint(f);
  u += 0x7FFFu + ((u >> 16) & 1u);   // round-to-nearest-even
  return (unsigned short)(u >> 16);
}

DEVINL void gload16(const void* g, void* l) {
  __builtin_amdgcn_global_load_lds((void_g*)g, (void_l*)l, 16, 0, 0);
}

DEVINL float wave_sum(float v) {
  #pragma unroll
  for (int o = 32; o > 0; o >>= 1) v += __shfl_down(v, o, 64);
  return v;
}
DEVINL float wave_max(float v) {
  #pragma unroll
  for (int o = 32; o > 0; o >>= 1) v = fmaxf(v, __shfl_down(v, o, 64));
  return v;
}

// ---------------- sum(|w|) over fp32 tensor -> double ----------------
__global__ __launch_bounds__(256) void absum_kernel(const float* __restrict__ w,
                                                    long long nchunk, double* __restrict__ out) {
  long long stride = (long long)gridDim.x * 256;
  long long i = (long long)blockIdx.x * 256 + threadIdx.x;
  float s = 0.f;
  for (; i < nchunk; i += stride) {
    f32x4 v = ((const f32x4*)w)[i];
    s += fabsf(v[0]) + fabsf(v[1]) + fabsf(v[2]) + fabsf(v[3]);
  }
  s = wave_sum(s);
  __shared__ float red[4];
  int lane = threadIdx.x & 63, wv = threadIdx.x >> 6;
  if (lane == 0) red[wv] = s;
  __syncthreads();
  if (threadIdx.x == 0) atomicAdd(out, (double)(red[0] + red[1] + red[2] + red[3]));
}

// ---------------- ternary weight quant: tern = clip(round(w/mean|w|),-1,1) as bf16 ----------------
__global__ __launch_bounds__(256) void quantw_kernel(const float* __restrict__ w,
                                                     unsigned short* __restrict__ tern,
                                                     long long nchunk,  // groups of 8 floats
                                                     const double* __restrict__ sum, double inv_n) {
  float scale = (float)(1.0 / fmax(*sum * inv_n, 1e-5));
  long long stride = (long long)gridDim.x * 256;
  long long i = (long long)blockIdx.x * 256 + threadIdx.x;
  for (; i < nchunk; i += stride) {
    f32x4 v0 = ((const f32x4*)w)[2 * i];
    f32x4 v1 = ((const f32x4*)w)[2 * i + 1];
    u32x4 o;
    #pragma unroll
    for (int k = 0; k < 4; k++) {
      float a = fminf(fmaxf(rintf((k < 2 ? v0[2 * k] : v1[2 * k - 4]) * scale), -1.f), 1.f);
      float b = fminf(fmaxf(rintf((k < 2 ? v0[2 * k + 1] : v1[2 * k - 3]) * scale), -1.f), 1.f);
      o[k] = (unsigned int)f2bf(a) | ((unsigned int)f2bf(b) << 16);
    }
    ((u32x4*)tern)[i] = o;
  }
}

// ---------------- RMSNorm + per-token int8 absmax quant (H=2048), fp32 in, bf16-int out ----------------
__global__ __launch_bounds__(256) void actq1_kernel(const float* __restrict__ x,
                                                    const float* __restrict__ g,
                                                    unsigned short* __restrict__ q,
                                                    float* __restrict__ a) {
  int t = blockIdx.x, tid = threadIdx.x;
  int lane = tid & 63, wv = tid >> 6;
  __shared__ float redS[4], redM[4];

  const f32x4* xr = (const f32x4*)(x + (size_t)t * 2048);
  f32x4 v0 = xr[tid * 2], v1 = xr[tid * 2 + 1];
  float ssq = 0.f;
  #pragma unroll
  for (int k = 0; k < 4; k++) ssq += v0[k] * v0[k] + v1[k] * v1[k];
  float ws_ = wave_sum(ssq);
  if (lane == 0) redS[wv] = ws_;
  __syncthreads();
  float tot = redS[0] + redS[1] + redS[2] + redS[3];
  float r = rsqrtf(tot / 2048.f + 1e-8f);

  f32x4 g0 = ((const f32x4*)g)[tid * 2], g1 = ((const f32x4*)g)[tid * 2 + 1];
  float h[8], amax = 0.f;
  #pragma unroll
  for (int k = 0; k < 4; k++) {
    h[k]     = v0[k] * r * g0[k];
    h[4 + k] = v1[k] * r * g1[k];
    amax = fmaxf(amax, fmaxf(fabsf(h[k]), fabsf(h[4 + k])));
  }
  float wm = wave_max(amax);
  if (lane == 0) redM[wv] = wm;
  __syncthreads();
  float am = fmaxf(fmaxf(fmaxf(redM[0], redM[1]), fmaxf(redM[2], redM[3])), 1e-5f);
  float scale = 127.f / am;

  u32x4 o;
  #pragma unroll
  for (int k = 0; k < 4; k++) {
    float q0 = fminf(fmaxf(rintf(h[2 * k] * scale), -128.f), 127.f);
    float q1 = fminf(fmaxf(rintf(h[2 * k + 1] * scale), -128.f), 127.f);
    o[k] = (unsigned int)f2bf(q0) | ((unsigned int)f2bf(q1) << 16);
  }
  *((u32x4*)(q + (size_t)t * 2048) + tid) = o;
  if (tid == 0) a[t] = am / 127.f;
}

// ---------------- SiLU(gate)*up + RMSNorm + quant (I=8192); y fp16 [T,16384], g fp32 ----------------
__global__ __launch_bounds__(256) void silu_rms_q_kernel(const unsigned short* __restrict__ y,
                                                         const float* __restrict__ g,
                                                         unsigned short* __restrict__ q2,
                                                         float* __restrict__ a2) {
  int t = blockIdx.x, tid = threadIdx.x;
  int lane = tid & 63, wv = tid >> 6;
  __shared__ float redS[4], redM[4];
  const u32x4* gate = (const u32x4*)(y + (size_t)t * 16384);
  const u32x4* up   = (const u32x4*)(y + (size_t)t * 16384 + 8192);

  float v[32];
  float ssq = 0.f;
  #pragma unroll
  for (int b = 0; b < 4; b++) {
    u32x4 gr = gate[b * 256 + tid];
    u32x4 ur = up[b * 256 + tid];
    #pragma unroll
    for (int k = 0; k < 4; k++) {
      float g0 = __half2float(__ushort_as_half((unsigned short)(gr[k] & 0xFFFFu)));
      float g1 = __half2float(__ushort_as_half((unsigned short)(gr[k] >> 16)));
      float u0 = __half2float(__ushort_as_half((unsigned short)(ur[k] & 0xFFFFu)));
      float u1 = __half2float(__ushort_as_half((unsigned short)(ur[k] >> 16)));
      float v0 = g0 / (1.f + expf(-g0)) * u0;
      float v1 = g1 / (1.f + expf(-g1)) * u1;
      v[b * 8 + 2 * k] = v0;
      v[b * 8 + 2 * k + 1] = v1;
      ssq += v0 * v0 + v1 * v1;
    }
  }
  float ws_ = wave_sum(ssq);
  if (lane == 0) redS[wv] = ws_;
  __syncthreads();
  float tot = redS[0] + redS[1] + redS[2] + redS[3];
  float r = rsqrtf(tot / 8192.f + 1e-8f);

  float amax = 0.f;
  #pragma unroll
  for (int b = 0; b < 4; b++) {
    f32x4 ga = ((const f32x4*)g)[b * 512 + tid * 2];
    f32x4 gb = ((const f32x4*)g)[b * 512 + tid * 2 + 1];
    #pragma unroll
    for (int k = 0; k < 4; k++) {
      float h0 = v[b * 8 + k]     * r * ga[k];   // careful: keep element order
      float h1 = v[b * 8 + 4 + k] * r * gb[k];
      v[b * 8 + k] = h0;
      v[b * 8 + 4 + k] = h1;
      amax = fmaxf(amax, fmaxf(fabsf(h0), fabsf(h1)));
    }
  }
  float wm = wave_max(amax);
  if (lane == 0) redM[wv] = wm;
  __syncthreads();
  float am = fmaxf(fmaxf(fmaxf(redM[0], redM[1]), fmaxf(redM[2], redM[3])), 1e-5f);
  float scale = 127.f / am;

  #pragma unroll
  for (int b = 0; b < 4; b++) {
    u32x4 o;
    #pragma unroll
    for (int k = 0; k < 4; k++) {
      float q0 = fminf(fmaxf(rintf(v[b * 8 + 2 * k] * scale), -128.f), 127.f);
      float q1 = fminf(fmaxf(rintf(v[b * 8 + 2 * k + 1] * scale), -128.f), 127.f);
      o[k] = (unsigned int)f2bf(q0) | ((unsigned int)f2bf(q1) << 16);
    }
    ((u32x4*)(q2 + (size_t)t * 8192))[b * 256 + tid] = o;
  }
  if (tid == 0) a2[t] = am / 127.f;
}

// ---------------- m97-style GEMM: C[M,N] = A[M,K] * B[N,K]^T, per-row scaled ----------------
// A,B bf16 holding exact small ints -> fp32 MFMA accumulation is exact.
// OUT_MODE: 0 = fp16 (ushort), 1 = fp32 (float)
template <int OUT_MODE>
__global__ __launch_bounds__(256) void gemm_bt_kernel(const unsigned short* __restrict__ A,
                                                      const unsigned short* __restrict__ B,
                                                      void* __restrict__ Cv,
                                                      int M, int N, int K,
                                                      const float* __restrict__ rowscale,
                                                      const double* __restrict__ wsum, double inv_n) {
  __shared__ unsigned short As[4096];  // 128 rows x 32 cols
  __shared__ unsigned short Bs[4096];
  const int tid = threadIdx.x;
  const int lane = tid & 63;
  const int wv = tid >> 6;
  const int wm = wv >> 1, wn = wv & 1;
  const int m0 = blockIdx.y * 128;
  const int n0 = blockIdx.x * 128;

  const int rr = tid >> 2;
  const int cc = (tid & 3) * 8;
  const unsigned short* Ag0 = A + (size_t)(m0 + rr) * K + cc;
  const unsigned short* Ag1 = A + (size_t)(m0 + 64 + rr) * K + cc;
  const unsigned short* Bg0 = B + (size_t)(n0 + rr) * K + cc;
  const unsigned short* Bg1 = B + (size_t)(n0 + 64 + rr) * K + cc;
  unsigned short* lA0 = &As[tid * 8];
  unsigned short* lA1 = &As[2048 + tid * 8];
  unsigned short* lB0 = &Bs[tid * 8];
  unsigned short* lB1 = &Bs[2048 + tid * 8];

  f32x4 acc[4][4] = {};

  const int fr = (lane & 15);
  const int kof = (lane >> 4) * 8;

  for (int k0 = 0; k0 < K; k0 += 32) {
    gload16(Ag0 + k0, lA0);
    gload16(Ag1 + k0, lA1);
    gload16(Bg0 + k0, lB0);
    gload16(Bg1 + k0, lB1);
    __syncthreads();
    bf16x8 af[4], bfr[4];
    #pragma unroll
    for (int i = 0; i < 4; i++)
      af[i] = *(const bf16x8*)&As[(wm * 64 + i * 16 + fr) * 32 + kof];
    #pragma unroll
    for (int j = 0; j < 4; j++)
      bfr[j] = *(const bf16x8*)&Bs[(wn * 64 + j * 16 + fr) * 32 + kof];
    #pragma unroll
    for (int i = 0; i < 4; i++)
      #pragma unroll
      for (int j = 0; j < 4; j++)
        acc[i][j] = __builtin_amdgcn_mfma_f32_16x16x32_bf16(af[i], bfr[j], acc[i][j], 0, 0, 0);
    __syncthreads();
  }

  float sw = (float)fmax(*wsum * inv_n, 1e-5);
  const int q = lane >> 4;
  const int cbase = n0 + wn * 64 + (lane & 15);
  #pragma unroll
  for (int i = 0; i < 4; i++) {
    int rowb = m0 + wm * 64 + i * 16 + q * 4;
    #pragma unroll
    for (int r = 0; r < 4; r++) {
      float sc = rowscale[rowb + r] * sw;
      size_t off = (size_t)(rowb + r) * N + cbase;
      #pragma unroll
      for (int j = 0; j < 4; j++) {
        float vv = acc[i][j][r] * sc;
        if (OUT_MODE == 0) ((unsigned short*)Cv)[off + j * 16] = __half_as_ushort(__float2half(vv));
        else               ((float*)Cv)[off + j * 16] = vv;
      }
    }
  }
}

extern "C" void kernel_launch(void* const* d_in, const int* in_sizes, int n_in,
                              void* d_out, int out_size, void* d_ws, size_t ws_size,
                              hipStream_t stream) {
  const float* x      = (const float*)d_in[0];
  const float* w_gate = (const float*)d_in[1];
  const float* g_gate = (const float*)d_in[2];
  const float* w_down = (const float*)d_in[3];
  const float* g_down = (const float*)d_in[4];
  float* out = (float*)d_out;

  char* ws = (char*)d_ws;
  double* sums = (double*)ws;                                    // 2 doubles
  float* a1 = (float*)(ws + 4096);                               // 4096 f32
  float* a2 = (float*)(ws + 4096 + 16384);                       // 4096 f32
  unsigned short* tern_g = (unsigned short*)(ws + 65536);        // 16384x2048 bf16 = 64 MiB
  unsigned short* q2     = tern_g;                               // alias: tern_g dead after GEMM1
  unsigned short* tern_d = (unsigned short*)(ws + 65536 + 67108864);   // 2048x8192 bf16 = 32 MiB
  unsigned short* q1     = (unsigned short*)(ws + 65536 + 100663296);  // 4096x2048 bf16 = 16 MiB
  unsigned short* yh     = (unsigned short*)(ws + 65536 + 117440512);  // 4096x16384 fp16 = 128 MiB

  hipMemsetAsync(sums, 0, 16, stream);
  absum_kernel<<<2048, 256, 0, stream>>>(w_gate, 33554432LL / 4, sums + 0);
  absum_kernel<<<1024, 256, 0, stream>>>(w_down, 16777216LL / 4, sums + 1);
  quantw_kernel<<<4096, 256, 0, stream>>>(w_gate, tern_g, 33554432LL / 8, sums + 0, 1.0 / 33554432.0);
  quantw_kernel<<<2048, 256, 0, stream>>>(w_down, tern_d, 16777216LL / 8, sums + 1, 1.0 / 16777216.0);
  actq1_kernel<<<4096, 256, 0, stream>>>(x, g_gate, q1, a1);
  gemm_bt_kernel<0><<<dim3(128, 32), 256, 0, stream>>>(q1, tern_g, yh, 4096, 16384, 2048,
                                                       a1, sums + 0, 1.0 / 33554432.0);
  silu_rms_q_kernel<<<4096, 256, 0, stream>>>(yh, g_down, q2, a2);
  gemm_bt_kernel<1><<<dim3(16, 32), 256, 0, stream>>>(q2, tern_d, out, 4096, 2048, 8192,
                                                      a2, sums + 1, 1.0 / 16777216.0);
}

// Round 3
// 657.405 us; speedup vs baseline: 1.4334x; 1.4334x over previous
//
#include <hip/hip_runtime.h>
#include <hip/hip_bf16.h>
#include <hip/hip_fp16.h>

#define DEVINL __device__ __forceinline__

typedef float f32x4 __attribute__((ext_vector_type(4)));
typedef int i32x4 __attribute__((ext_vector_type(4)));
typedef unsigned int u32x4 __attribute__((ext_vector_type(4)));
typedef unsigned int u32x2 __attribute__((ext_vector_type(2)));

typedef __attribute__((address_space(1))) void void_g;
typedef __attribute__((address_space(3))) void void_l;

DEVINL void gload16(const void* g, void* l) {
  // async global->LDS, 16B/lane; LDS dst must be wave-uniform base + lane*16
  __builtin_amdgcn_global_load_lds((void_g*)g, (void_l*)l, 16, 0, 0);
}

DEVINL float wave_sum(float v) {
  #pragma unroll
  for (int o = 32; o > 0; o >>= 1) v += __shfl_down(v, o, 64);
  return v;
}
DEVINL float wave_max(float v) {
  #pragma unroll
  for (int o = 32; o > 0; o >>= 1) v = fmaxf(v, __shfl_down(v, o, 64));
  return v;
}

// pack 4 already-rounded-and-clamped floats into 4 signed bytes
DEVINL unsigned int pack4(float a, float b, float c, float d) {
  return ((unsigned int)(unsigned char)(signed char)(int)a)
       | (((unsigned int)(unsigned char)(signed char)(int)b) << 8)
       | (((unsigned int)(unsigned char)(signed char)(int)c) << 16)
       | (((unsigned int)(unsigned char)(signed char)(int)d) << 24);
}

// ---------------- sum(|w|) over fp32 tensor -> double ----------------
__global__ __launch_bounds__(256) void absum_kernel(const float* __restrict__ w,
                                                    long long nchunk, double* __restrict__ out) {
  long long stride = (long long)gridDim.x * 256;
  long long i = (long long)blockIdx.x * 256 + threadIdx.x;
  float s = 0.f;
  for (; i < nchunk; i += stride) {
    f32x4 v = ((const f32x4*)w)[i];
    s += fabsf(v[0]) + fabsf(v[1]) + fabsf(v[2]) + fabsf(v[3]);
  }
  s = wave_sum(s);
  __shared__ float red[4];
  int lane = threadIdx.x & 63, wv = threadIdx.x >> 6;
  if (lane == 0) red[wv] = s;
  __syncthreads();
  if (threadIdx.x == 0) atomicAdd(out, (double)(red[0] + red[1] + red[2] + red[3]));
}

// ---------------- ternary weight quant -> int8 {-1,0,1} ----------------
__global__ __launch_bounds__(256) void quantw_kernel(const float* __restrict__ w,
                                                     signed char* __restrict__ tern,
                                                     long long nchunk,  // groups of 8 floats
                                                     const double* __restrict__ sum, double inv_n) {
  float scale = (float)(1.0 / fmax(*sum * inv_n, 1e-5));
  long long stride = (long long)gridDim.x * 256;
  long long i = (long long)blockIdx.x * 256 + threadIdx.x;
  for (; i < nchunk; i += stride) {
    f32x4 v0 = ((const f32x4*)w)[2 * i];
    f32x4 v1 = ((const f32x4*)w)[2 * i + 1];
    float t[8];
    #pragma unroll
    for (int k = 0; k < 4; k++) {
      t[k]     = fminf(fmaxf(rintf(v0[k] * scale), -1.f), 1.f);
      t[4 + k] = fminf(fmaxf(rintf(v1[k] * scale), -1.f), 1.f);
    }
    u32x2 o;
    o[0] = pack4(t[0], t[1], t[2], t[3]);
    o[1] = pack4(t[4], t[5], t[6], t[7]);
    ((u32x2*)tern)[i] = o;
  }
}

// ---------------- RMSNorm + per-token int8 absmax quant (H=2048) ----------------
__global__ __launch_bounds__(256) void actq1_kernel(const float* __restrict__ x,
                                                    const float* __restrict__ g,
                                                    signed char* __restrict__ q,
                                                    float* __restrict__ a) {
  int t = blockIdx.x, tid = threadIdx.x;
  int lane = tid & 63, wv = tid >> 6;
  __shared__ float redS[4], redM[4];

  const f32x4* xr = (const f32x4*)(x + (size_t)t * 2048);
  f32x4 v0 = xr[tid * 2], v1 = xr[tid * 2 + 1];
  float ssq = 0.f;
  #pragma unroll
  for (int k = 0; k < 4; k++) ssq += v0[k] * v0[k] + v1[k] * v1[k];
  float ws_ = wave_sum(ssq);
  if (lane == 0) redS[wv] = ws_;
  __syncthreads();
  float tot = redS[0] + redS[1] + redS[2] + redS[3];
  float r = rsqrtf(tot / 2048.f + 1e-8f);

  f32x4 g0 = ((const f32x4*)g)[tid * 2], g1 = ((const f32x4*)g)[tid * 2 + 1];
  float h[8], amax = 0.f;
  #pragma unroll
  for (int k = 0; k < 4; k++) {
    h[k]     = v0[k] * r * g0[k];
    h[4 + k] = v1[k] * r * g1[k];
    amax = fmaxf(amax, fmaxf(fabsf(h[k]), fabsf(h[4 + k])));
  }
  float wm = wave_max(amax);
  if (lane == 0) redM[wv] = wm;
  __syncthreads();
  float am = fmaxf(fmaxf(fmaxf(redM[0], redM[1]), fmaxf(redM[2], redM[3])), 1e-5f);
  float scale = 127.f / am;

  float qv[8];
  #pragma unroll
  for (int k = 0; k < 8; k++) qv[k] = fminf(fmaxf(rintf(h[k] * scale), -128.f), 127.f);
  u32x2 o;
  o[0] = pack4(qv[0], qv[1], qv[2], qv[3]);
  o[1] = pack4(qv[4], qv[5], qv[6], qv[7]);
  ((u32x2*)(q + (size_t)t * 2048))[tid] = o;
  if (tid == 0) a[t] = am / 127.f;
}

// ---------------- SiLU(gate)*up + RMSNorm + quant (I=8192); y fp16 [T,16384] ----------------
__global__ __launch_bounds__(256) void silu_rms_q_kernel(const unsigned short* __restrict__ y,
                                                         const float* __restrict__ g,
                                                         signed char* __restrict__ q2,
                                                         float* __restrict__ a2) {
  int t = blockIdx.x, tid = threadIdx.x;
  int lane = tid & 63, wv = tid >> 6;
  __shared__ float redS[4], redM[4];
  const u32x4* gate = (const u32x4*)(y + (size_t)t * 16384);
  const u32x4* up   = (const u32x4*)(y + (size_t)t * 16384 + 8192);

  float v[32];
  float ssq = 0.f;
  #pragma unroll
  for (int b = 0; b < 4; b++) {
    u32x4 gr = gate[b * 256 + tid];
    u32x4 ur = up[b * 256 + tid];
    #pragma unroll
    for (int k = 0; k < 4; k++) {
      float g0 = __half2float(__ushort_as_half((unsigned short)(gr[k] & 0xFFFFu)));
      float g1 = __half2float(__ushort_as_half((unsigned short)(gr[k] >> 16)));
      float u0 = __half2float(__ushort_as_half((unsigned short)(ur[k] & 0xFFFFu)));
      float u1 = __half2float(__ushort_as_half((unsigned short)(ur[k] >> 16)));
      float v0 = g0 / (1.f + expf(-g0)) * u0;
      float v1 = g1 / (1.f + expf(-g1)) * u1;
      v[b * 8 + 2 * k] = v0;
      v[b * 8 + 2 * k + 1] = v1;
      ssq += v0 * v0 + v1 * v1;
    }
  }
  float ws_ = wave_sum(ssq);
  if (lane == 0) redS[wv] = ws_;
  __syncthreads();
  float tot = redS[0] + redS[1] + redS[2] + redS[3];
  float r = rsqrtf(tot / 8192.f + 1e-8f);

  float amax = 0.f;
  #pragma unroll
  for (int b = 0; b < 4; b++) {
    f32x4 ga = ((const f32x4*)g)[b * 512 + tid * 2];
    f32x4 gb = ((const f32x4*)g)[b * 512 + tid * 2 + 1];
    #pragma unroll
    for (int k = 0; k < 4; k++) {
      float h0 = v[b * 8 + k]     * r * ga[k];
      float h1 = v[b * 8 + 4 + k] * r * gb[k];
      v[b * 8 + k] = h0;
      v[b * 8 + 4 + k] = h1;
      amax = fmaxf(amax, fmaxf(fabsf(h0), fabsf(h1)));
    }
  }
  float wm = wave_max(amax);
  if (lane == 0) redM[wv] = wm;
  __syncthreads();
  float am = fmaxf(fmaxf(fmaxf(redM[0], redM[1]), fmaxf(redM[2], redM[3])), 1e-5f);
  float scale = 127.f / am;

  #pragma unroll
  for (int b = 0; b < 4; b++) {
    float qv[8];
    #pragma unroll
    for (int k = 0; k < 8; k++)
      qv[k] = fminf(fmaxf(rintf(v[b * 8 + k] * scale), -128.f), 127.f);
    u32x2 o;
    o[0] = pack4(qv[0], qv[1], qv[2], qv[3]);
    o[1] = pack4(qv[4], qv[5], qv[6], qv[7]);
    ((u32x2*)(q2 + (size_t)t * 8192))[b * 256 + tid] = o;
  }
  if (tid == 0) a2[t] = am / 127.f;
}

// ---------------- int8 MFMA GEMM: C[M,N] = A[M,K] * B[N,K]^T, per-row scaled ----------------
// A int8 activations, B ternary int8; i32 accumulation exact (|acc| <= 2^20 < 2^24).
// OUT_MODE: 0 = fp16 (ushort), 1 = fp32 (float)
template <int OUT_MODE>
__global__ __launch_bounds__(256) void gemm_i8_kernel(const signed char* __restrict__ A,
                                                      const signed char* __restrict__ B,
                                                      void* __restrict__ Cv,
                                                      int M, int N, int K,
                                                      const float* __restrict__ rowscale,
                                                      const double* __restrict__ wsum, double inv_n) {
  __shared__ signed char As[8192];  // 128 rows x 64 cols (i8)
  __shared__ signed char Bs[8192];
  const int tid = threadIdx.x;
  const int lane = tid & 63;
  const int wv = tid >> 6;
  const int wm = wv >> 1, wn = wv & 1;
  const int m0 = blockIdx.y * 128;
  const int n0 = blockIdx.x * 128;

  const int rr = tid >> 2;            // staging row within 64-row half
  const int cc = (tid & 3) * 16;      // staging col (bytes)
  const signed char* Ag0 = A + (size_t)(m0 + rr) * K + cc;
  const signed char* Ag1 = A + (size_t)(m0 + 64 + rr) * K + cc;
  const signed char* Bg0 = B + (size_t)(n0 + rr) * K + cc;
  const signed char* Bg1 = B + (size_t)(n0 + 64 + rr) * K + cc;
  signed char* lA0 = &As[tid * 16];
  signed char* lA1 = &As[4096 + tid * 16];
  signed char* lB0 = &Bs[tid * 16];
  signed char* lB1 = &Bs[4096 + tid * 16];

  i32x4 acc[4][4] = {};

  const int fr = (lane & 15);
  const int kof = (lane >> 4) * 16;   // byte offset along K within a row

  for (int k0 = 0; k0 < K; k0 += 64) {
    gload16(Ag0 + k0, lA0);
    gload16(Ag1 + k0, lA1);
    gload16(Bg0 + k0, lB0);
    gload16(Bg1 + k0, lB1);
    __syncthreads();
    i32x4 af[4], bfr[4];
    #pragma unroll
    for (int i = 0; i < 4; i++)
      af[i] = *(const i32x4*)&As[(wm * 64 + i * 16 + fr) * 64 + kof];
    #pragma unroll
    for (int j = 0; j < 4; j++)
      bfr[j] = *(const i32x4*)&Bs[(wn * 64 + j * 16 + fr) * 64 + kof];
    #pragma unroll
    for (int i = 0; i < 4; i++)
      #pragma unroll
      for (int j = 0; j < 4; j++)
        acc[i][j] = __builtin_amdgcn_mfma_i32_16x16x64_i8(af[i], bfr[j], acc[i][j], 0, 0, 0);
    __syncthreads();
  }

  float sw = (float)fmax(*wsum * inv_n, 1e-5);
  const int q = lane >> 4;
  const int cbase = n0 + wn * 64 + (lane & 15);
  #pragma unroll
  for (int i = 0; i < 4; i++) {
    int rowb = m0 + wm * 64 + i * 16 + q * 4;
    #pragma unroll
    for (int r = 0; r < 4; r++) {
      float sc = rowscale[rowb + r] * sw;
      size_t off = (size_t)(rowb + r) * N + cbase;
      #pragma unroll
      for (int j = 0; j < 4; j++) {
        float vv = (float)acc[i][j][r] * sc;
        if (OUT_MODE == 0) ((unsigned short*)Cv)[off + j * 16] = __half_as_ushort(__float2half(vv));
        else               ((float*)Cv)[off + j * 16] = vv;
      }
    }
  }
}

extern "C" void kernel_launch(void* const* d_in, const int* in_sizes, int n_in,
                              void* d_out, int out_size, void* d_ws, size_t ws_size,
                              hipStream_t stream) {
  const float* x      = (const float*)d_in[0];
  const float* w_gate = (const float*)d_in[1];
  const float* g_gate = (const float*)d_in[2];
  const float* w_down = (const float*)d_in[3];
  const float* g_down = (const float*)d_in[4];
  float* out = (float*)d_out;

  char* ws = (char*)d_ws;
  double* sums = (double*)ws;                                    // 2 doubles
  float* a1 = (float*)(ws + 4096);                               // 4096 f32
  float* a2 = (float*)(ws + 20480);                              // 4096 f32
  const size_t MB = 1024 * 1024;
  signed char* tern_g = (signed char*)(ws + 65536);              // 16384x2048 i8 = 32 MiB
  signed char* q2     = tern_g;                                  // alias: tern_g dead after GEMM1 (32 MiB)
  signed char* tern_d = (signed char*)(ws + 65536 + 32 * MB);    // 2048x8192 i8 = 16 MiB
  signed char* q1     = (signed char*)(ws + 65536 + 48 * MB);    // 4096x2048 i8 = 8 MiB
  unsigned short* yh  = (unsigned short*)(ws + 65536 + 56 * MB); // 4096x16384 fp16 = 128 MiB

  hipMemsetAsync(sums, 0, 16, stream);
  absum_kernel<<<2048, 256, 0, stream>>>(w_gate, 33554432LL / 4, sums + 0);
  absum_kernel<<<1024, 256, 0, stream>>>(w_down, 16777216LL / 4, sums + 1);
  quantw_kernel<<<4096, 256, 0, stream>>>(w_gate, tern_g, 33554432LL / 8, sums + 0, 1.0 / 33554432.0);
  quantw_kernel<<<2048, 256, 0, stream>>>(w_down, tern_d, 16777216LL / 8, sums + 1, 1.0 / 16777216.0);
  actq1_kernel<<<4096, 256, 0, stream>>>(x, g_gate, q1, a1);
  gemm_i8_kernel<0><<<dim3(128, 32), 256, 0, stream>>>(q1, tern_g, yh, 4096, 16384, 2048,
                                                       a1, sums + 0, 1.0 / 33554432.0);
  silu_rms_q_kernel<<<4096, 256, 0, stream>>>(yh, g_down, q2, a2);
  gemm_i8_kernel<1><<<dim3(16, 32), 256, 0, stream>>>(q2, tern_d, out, 4096, 2048, 8192,
                                                      a2, sums + 1, 1.0 / 16777216.0);
}